// Round 4
// baseline (356.842 us; speedup 1.0000x reference)
//
#include <hip/hip_runtime.h>
#include <hip/hip_bf16.h>

// VQ-VAE vector quantizer: B=32768, K=4096, D=256 (fp32)
// out = [quantized (B*D floats), vq_loss (1 float)]
//
//  xconv : X -> fp16 hi/lo, swizzled into d_out (32MB, overwritten later by rescore)
//  econv : E -> NEGATED fp16 (hi only), swizzled into ws
//  en2ext: ext K-slice frags {0.5||e||^2 hi/lo fp16 at k=0,1} into ws
//  dist4 : fp16 2-term MFMA GEMM (S = xh*(-eh) + xl*(-eh)), 9th ext phase adds
//          0.5||e||^2  ->  acc = 0.5||e||^2 - x.e ; per-row top-2 per 1024-chunk
//  rescore: fp64 rescore of 8 candidates -> exact winner, gather, loss partials
//  finalize: loss = 1.25 * mean((x-q)^2)

#define B_N 32768
#define K_N 4096
#define D_N 256
#define NCH 4

typedef _Float16 f16x8 __attribute__((ext_vector_type(8)));
typedef float f32x4 __attribute__((ext_vector_type(4)));
typedef unsigned int uint4v __attribute__((ext_vector_type(4)));
typedef unsigned short u16;

// ws layout (~4.8 MB; R3 proved ws >= 6.3 MB)
static constexpr size_t P_TOP2 = 0;                                  // 32768*4*16 = 2 MB
static constexpr size_t P_ESW  = (size_t)B_N * NCH * 16;             // +2 MB (fp16 hi only)
static constexpr size_t P_EXT  = P_ESW + (size_t)K_N * D_N * 2;      // +256 KB
static constexpr size_t P_PART = P_EXT + 16 * 16384;                 // +4 KB

__device__ __forceinline__ u16 f2h(float f) {
    _Float16 h = (_Float16)f;
    return __builtin_bit_cast(u16, h);
}
__device__ __forceinline__ float h2f(u16 u) {
    return (float)__builtin_bit_cast(_Float16, u);
}

__device__ __forceinline__ void gload_lds16(const void* g, void* l) {
    __builtin_amdgcn_global_load_lds(
        (const __attribute__((address_space(1))) void*)g,
        (__attribute__((address_space(3))) void*)l, 16, 0, 0);
}

#define WAITVM4() asm volatile("s_waitcnt vmcnt(4)" ::: "memory")
#define WAITVM8() asm volatile("s_waitcnt vmcnt(8)" ::: "memory")
#define BARRIER() __builtin_amdgcn_s_barrier()

__device__ __forceinline__ void top2_merge(float& v0, int& i0, float& v1, int& i1,
                                           float ov0, int oi0, float ov1, int oi1) {
    bool bf_ = (ov0 < v0) || (ov0 == v0 && oi0 < i0);
    float w0v = bf_ ? ov0 : v0;  int w0i = bf_ ? oi0 : i0;
    float lv  = bf_ ? v0  : ov0; int li  = bf_ ? i0  : oi0;
    float cv  = bf_ ? ov1 : v1;  int ci  = bf_ ? oi1 : i1;
    bool tl = (lv < cv) || (lv == cv && li < ci);
    v0 = w0v; i0 = w0i;
    v1 = tl ? lv : cv; i1 = tl ? li : ci;
}

// ---------- xconv: X -> fp16 hi/lo swizzled ----------
// u16 off = (rb*8+h)*8192 + term*4096 + rf*512 + (lhi*16+llo)*8
// row = rb*128+rf*16+llo ; d = h*32 + lhi*8 + j
__global__ void xconv_kernel(const float* __restrict__ X, u16* __restrict__ Xsw) {
    const int gid = blockIdx.x * 256 + threadIdx.x;     // B_N*32 threads
    const int row = gid >> 5;
    const int d0  = (gid & 31) << 3;
    const float4 a = *reinterpret_cast<const float4*>(X + (size_t)row * D_N + d0);
    const float4 b = *reinterpret_cast<const float4*>(X + (size_t)row * D_N + d0 + 4);
    float f[8] = {a.x, a.y, a.z, a.w, b.x, b.y, b.z, b.w};
    unsigned hi[8], lo[8];
    #pragma unroll
    for (int j = 0; j < 8; ++j) {
        hi[j] = f2h(f[j]);
        lo[j] = f2h(f[j] - h2f((u16)hi[j]));
    }
    const int rb = row >> 7, rr = row & 127, rf = rr >> 4, llo = rr & 15;
    const int h = d0 >> 5, lhi = (d0 & 31) >> 3, lane = lhi * 16 + llo;
    size_t base = (size_t)(rb * 8 + h) * 8192 + (size_t)rf * 512 + (size_t)lane * 8;
    uint4v hv, lv;
    hv.x = hi[0] | (hi[1] << 16); hv.y = hi[2] | (hi[3] << 16);
    hv.z = hi[4] | (hi[5] << 16); hv.w = hi[6] | (hi[7] << 16);
    lv.x = lo[0] | (lo[1] << 16); lv.y = lo[2] | (lo[3] << 16);
    lv.z = lo[4] | (lo[5] << 16); lv.w = lo[6] | (lo[7] << 16);
    *reinterpret_cast<uint4v*>(Xsw + base) = hv;
    *reinterpret_cast<uint4v*>(Xsw + base + 4096) = lv;   // term 1 (lo)
}

// ---------- econv: E -> negated fp16 hi, swizzled ----------
// u16 off = (cbg2*8+h)*8192 + cf*512 + (lhi*16+llo)*8 ; cbg2 = code>>8, cf = (code&255)>>4
__global__ void econv_kernel(const float* __restrict__ E, u16* __restrict__ Esw) {
    const int gid = blockIdx.x * 256 + threadIdx.x;     // K_N*32 threads
    const int code = gid >> 5;
    const int d0  = (gid & 31) << 3;
    const float4 a = *reinterpret_cast<const float4*>(E + (size_t)code * D_N + d0);
    const float4 b = *reinterpret_cast<const float4*>(E + (size_t)code * D_N + d0 + 4);
    float f[8] = {a.x, a.y, a.z, a.w, b.x, b.y, b.z, b.w};
    unsigned hi[8];
    #pragma unroll
    for (int j = 0; j < 8; ++j) hi[j] = f2h(-f[j]);
    const int cbg2 = code >> 8, cc = code & 255, cf = cc >> 4, llo = cc & 15;
    const int h = d0 >> 5, lhi = (d0 & 31) >> 3, lane = lhi * 16 + llo;
    size_t base = (size_t)(cbg2 * 8 + h) * 8192 + (size_t)cf * 512 + (size_t)lane * 8;
    uint4v hv;
    hv.x = hi[0] | (hi[1] << 16); hv.y = hi[2] | (hi[3] << 16);
    hv.z = hi[4] | (hi[5] << 16); hv.w = hi[6] | (hi[7] << 16);
    *reinterpret_cast<uint4v*>(Esw + base) = hv;
}

// ---------- en2ext: ext frags {0.5||e||^2 hi/lo at k=0,1} ----------
// u16 off = cbg2*8192 + cf*512 + flane*8 ; one wave per code
__global__ void en2ext_kernel(const float* __restrict__ E, u16* __restrict__ Eext) {
    const int gtid = blockIdx.x * 256 + threadIdx.x;
    const int code = gtid >> 6;
    const int lane = threadIdx.x & 63;
    if (code >= K_N) return;
    const float4 v = *reinterpret_cast<const float4*>(E + (size_t)code * D_N + lane * 4);
    double s = (double)v.x * v.x + (double)v.y * v.y + (double)v.z * v.z + (double)v.w * v.w;
    #pragma unroll
    for (int o = 32; o; o >>= 1) s += __shfl_xor(s, o, 64);
    float en2 = (float)(0.5 * s);
    unsigned uh = f2h(en2);
    unsigned ul = f2h(en2 - h2f((u16)uh));
    const int cbg2 = code >> 8, cc = code & 255, cf = cc >> 4, llo = cc & 15;
    if (lane < 4) {
        uint4v w; w.x = (lane == 0) ? (uh | (ul << 16)) : 0u; w.y = 0; w.z = 0; w.w = 0;
        u16* p = Eext + (size_t)cbg2 * 8192 + (size_t)cf * 512 + (size_t)(lane * 16 + llo) * 8;
        *reinterpret_cast<uint4v*>(p) = w;
    }
}

// ---------- dist4: fp16x2 pipelined MFMA GEMM + top-2 ----------
// grid (256 rb, 4 chunks), 256 thr (4 waves 2x2), block tile 128 rows x 256 codes,
// wave tile 64x128. LDS 64KB: buf b at b*32768 { X hi/lo 16K | E 16K }.
// Per cb (256 codes): phases p=0..7 (K=32 each) + p=8 ext (adds 0.5||e||^2).
// Ext frags are staged into next buffer's X region at p==7.
__launch_bounds__(256, 2)
__global__ void dist4_kernel(const char* __restrict__ Xsw, const char* __restrict__ Esw,
                             const char* __restrict__ Eext, float4* __restrict__ top2) {
    __shared__ __align__(16) char lds[65536];
    const int tid  = threadIdx.x;
    const int lane = tid & 63;
    const int wid  = tid >> 6;
    const int wr   = wid >> 1, wc = wid & 1;
    const int llo  = lane & 15, lhi = lane >> 4;
    const int rb = blockIdx.x;
    const int chunk = blockIdx.y;

    const char* xb = Xsw + (size_t)rb * 131072;                    // 8 h x 16KB
    const char* eb = Esw + (size_t)(chunk * 4) * 131072;           // 4 cb x 8 h x 16KB
    const char* xe = Eext + (size_t)(chunk * 4) * 16384;           // 4 cb x 16KB

    // ext A-frag: k=0,1 -> 1.0 fp16
    f16x8 aext;
    #pragma unroll
    for (int j = 0; j < 8; ++j) aext[j] = (_Float16)0.f;
    if (lane < 16) { aext[0] = (_Float16)1.f; aext[1] = (_Float16)1.f; }

    float tv0[16], tv1[16];
    int   tpk[16];
    #pragma unroll
    for (int s = 0; s < 16; ++s) { tv0[s] = 3.4e38f; tv1[s] = 3.4e38f; tpk[s] = -1; }

    f32x4 acc[4][8];
    #pragma unroll
    for (int i = 0; i < 4; ++i)
        #pragma unroll
        for (int j = 0; j < 8; ++j) acc[i][j] = (f32x4){0.f, 0.f, 0.f, 0.f};

    auto STAGE_XE = [&](int cb, int h, int buf) {
        const char* xs = xb + ((size_t)h << 14);
        const char* es = eb + (size_t)cb * 131072 + ((size_t)h << 14);
        char* lb = lds + buf * 32768;
        #pragma unroll
        for (int it = 0; it < 4; ++it)
            gload_lds16(xs + it * 4096 + tid * 16, lb + it * 4096 + wid * 1024);
        #pragma unroll
        for (int it = 0; it < 4; ++it)
            gload_lds16(es + it * 4096 + tid * 16, lb + 16384 + it * 4096 + wid * 1024);
    };
    auto STAGE_EXT = [&](int cb, int buf) {   // into buf's X region
        const char* s = xe + (size_t)cb * 16384;
        char* lb = lds + buf * 32768;
        #pragma unroll
        for (int it = 0; it < 4; ++it)
            gload_lds16(s + it * 4096 + tid * 16, lb + it * 4096 + wid * 1024);
    };

    STAGE_XE(0, 0, 0);
    int buf = 0;

    for (int cb = 0; cb < 4; ++cb) {
        #pragma unroll
        for (int p = 0; p < 9; ++p) {
            // stage next phase's data into buf^1
            if (p < 7)       STAGE_XE(cb, p + 1, buf ^ 1);
            else if (p == 7) STAGE_EXT(cb, buf ^ 1);
            else             STAGE_XE((cb + 1) & 3, 0, buf ^ 1);
            if (p == 8) { WAITVM8(); } else if (p == 7) { WAITVM4(); } else { WAITVM8(); }
            BARRIER();

            if (p < 8) {
                const f16x8* LX = reinterpret_cast<const f16x8*>(lds + buf * 32768);
                const f16x8* LE = reinterpret_cast<const f16x8*>(lds + buf * 32768 + 16384);
                f16x8 ah[4], al[4], bh[8];
                #pragma unroll
                for (int i = 0; i < 4; ++i) ah[i] = LX[(wr * 4 + i) * 64 + lane];
                #pragma unroll
                for (int j = 0; j < 8; ++j) bh[j] = LE[(wc * 8 + j) * 64 + lane];
                #pragma unroll
                for (int i = 0; i < 4; ++i) al[i] = LX[512 + (wr * 4 + i) * 64 + lane];

                __builtin_amdgcn_s_setprio(1);
                #pragma unroll
                for (int i = 0; i < 4; ++i)
                    #pragma unroll
                    for (int j = 0; j < 8; ++j)
                        acc[i][j] = __builtin_amdgcn_mfma_f32_16x16x32_f16(ah[i], bh[j], acc[i][j], 0, 0, 0);
                #pragma unroll
                for (int i = 0; i < 4; ++i)
                    #pragma unroll
                    for (int j = 0; j < 8; ++j)
                        acc[i][j] = __builtin_amdgcn_mfma_f32_16x16x32_f16(al[i], bh[j], acc[i][j], 0, 0, 0);
                __builtin_amdgcn_s_setprio(0);
            } else {
                // ext phase: acc += 0.5||e||^2 (frags in buf's X region)
                const f16x8* LT = reinterpret_cast<const f16x8*>(lds + buf * 32768);
                f16x8 be[8];
                #pragma unroll
                for (int j = 0; j < 8; ++j) be[j] = LT[(wc * 8 + j) * 64 + lane];
                __builtin_amdgcn_s_setprio(1);
                #pragma unroll
                for (int i = 0; i < 4; ++i)
                    #pragma unroll
                    for (int j = 0; j < 8; ++j)
                        acc[i][j] = __builtin_amdgcn_mfma_f32_16x16x32_f16(aext, be[j], acc[i][j], 0, 0, 0);
                __builtin_amdgcn_s_setprio(0);

                // epilogue: top-2 update; acc = 0.5||e||^2 - x.e
                const int codebase = chunk * 1024 + cb * 256;
                #pragma unroll
                for (int j = 0; j < 8; ++j) {
                    const int idx = codebase + (wc * 8 + j) * 16 + llo;
                    #pragma unroll
                    for (int i = 0; i < 4; ++i) {
                        #pragma unroll
                        for (int r = 0; r < 4; ++r) {
                            const float v = acc[i][j][r];
                            const int s = i * 4 + r;
                            const bool c0 = v < tv0[s];
                            const bool c1 = v < tv1[s];
                            const int pk = tpk[s];
                            const int pkA = (pk << 16) | idx;
                            const int pkB = (idx << 16) | (pk & 0xffff);
                            tv1[s] = c0 ? tv0[s] : (c1 ? v : tv1[s]);
                            tv0[s] = c0 ? v : tv0[s];
                            tpk[s] = c0 ? pkA : (c1 ? pkB : pk);
                        }
                    }
                }
                #pragma unroll
                for (int i = 0; i < 4; ++i)
                    #pragma unroll
                    for (int j = 0; j < 8; ++j) acc[i][j] = (f32x4){0.f, 0.f, 0.f, 0.f};
            }
            BARRIER();
            buf ^= 1;
        }
    }

    // cross-lane butterfly merge over the 16 column-lanes
    #pragma unroll
    for (int m = 1; m <= 8; m <<= 1) {
        #pragma unroll
        for (int s = 0; s < 16; ++s) {
            float ov0 = __shfl_xor(tv0[s], m, 64);
            float ov1 = __shfl_xor(tv1[s], m, 64);
            int   opk = __shfl_xor(tpk[s], m, 64);
            float v0 = tv0[s], v1 = tv1[s];
            int i0 = tpk[s] & 0xffff, i1 = (tpk[s] >> 16) & 0xffff;
            top2_merge(v0, i0, v1, i1, ov0, opk & 0xffff, ov1, (opk >> 16) & 0xffff);
            tv0[s] = v0; tv1[s] = v1; tpk[s] = (i1 << 16) | i0;
        }
    }

    __syncthreads();
    float4* M = reinterpret_cast<float4*>(lds);   // [128][2]
    if (llo == 0) {
        #pragma unroll
        for (int i = 0; i < 4; ++i)
            #pragma unroll
            for (int r = 0; r < 4; ++r) {
                const int rowl = wr * 64 + i * 16 + lhi * 4 + r;
                const int s = i * 4 + r;
                M[rowl * 2 + wc] = make_float4(tv0[s], __int_as_float(tpk[s] & 0xffff),
                                               tv1[s], __int_as_float((tpk[s] >> 16) & 0xffff));
            }
    }
    __syncthreads();
    if (tid < 128) {
        float4 A4 = M[tid * 2 + 0], B4 = M[tid * 2 + 1];
        float v0 = A4.x, v1 = A4.z;
        int i0 = __float_as_int(A4.y), i1 = __float_as_int(A4.w);
        top2_merge(v0, i0, v1, i1, B4.x, __float_as_int(B4.y), B4.z, __float_as_int(B4.w));
        top2[(size_t)(rb * 128 + tid) * NCH + chunk] =
            make_float4(v0, __int_as_float(i0), v1, __int_as_float(i1));
    }
}

// ---------- rescore: fp64 rescore of 8 candidates ----------
__global__ void rescore_kernel(const float* __restrict__ X, const float* __restrict__ E,
                               const float4* __restrict__ top2, float* __restrict__ out,
                               double* __restrict__ partials) {
    const int lane = threadIdx.x & 63;
    const int wid  = (blockIdx.x * blockDim.x + threadIdx.x) >> 6;
    const int nw   = (gridDim.x * blockDim.x) >> 6;
    double wloc = 0.0;

    for (int row = wid; row < B_N; row += nw) {
        int cand[8];
        #pragma unroll
        for (int c = 0; c < 4; ++c) {
            float4 t = top2[(size_t)row * NCH + c];
            cand[2 * c]     = __float_as_int(t.y);
            cand[2 * c + 1] = __float_as_int(t.w);
        }
        const float4 xv = *reinterpret_cast<const float4*>(X + (size_t)row * D_N + lane * 4);

        double bestd = 1e300; int besti = 0x7fffffff;
        float4 beste = make_float4(0.f, 0.f, 0.f, 0.f);
        #pragma unroll
        for (int c = 0; c < 8; ++c) {
            const int k = cand[c];
            const float4 ev = *reinterpret_cast<const float4*>(E + (size_t)k * D_N + lane * 4);
            double dx = (double)xv.x - (double)ev.x;
            double dy = (double)xv.y - (double)ev.y;
            double dz = (double)xv.z - (double)ev.z;
            double dw = (double)xv.w - (double)ev.w;
            double s = dx * dx + dy * dy + dz * dz + dw * dw;
            #pragma unroll
            for (int o = 32; o; o >>= 1) s += __shfl_xor(s, o, 64);
            if (s < bestd || (s == bestd && k < besti)) { bestd = s; besti = k; beste = ev; }
        }
        *reinterpret_cast<float4*>(out + (size_t)row * D_N + lane * 4) = beste;
        wloc += bestd;
    }

    __shared__ double bsum[8];
    const int widx = threadIdx.x >> 6;
    if (lane == 0) bsum[widx] = wloc;
    __syncthreads();
    if (threadIdx.x == 0) {
        double s = 0.0;
        for (int w = 0; w < (int)(blockDim.x >> 6); ++w) s += bsum[w];
        partials[blockIdx.x] = s;
    }
}

__global__ void finalize_kernel(const double* __restrict__ partials, int n,
                                float* __restrict__ loss_out) {
    __shared__ double sm[256];
    double s = 0.0;
    for (int i = threadIdx.x; i < n; i += 256) s += partials[i];
    sm[threadIdx.x] = s;
    __syncthreads();
    for (int st = 128; st; st >>= 1) {
        if (threadIdx.x < st) sm[threadIdx.x] += sm[threadIdx.x + st];
        __syncthreads();
    }
    if (threadIdx.x == 0)
        *loss_out = (float)(1.25 * sm[0] / (double)((size_t)B_N * D_N));
}

extern "C" void kernel_launch(void* const* d_in, const int* in_sizes, int n_in,
                              void* d_out, int out_size, void* d_ws, size_t ws_size,
                              hipStream_t stream) {
    const float* X = (const float*)d_in[0];
    const float* E = (const float*)d_in[1];
    float* out = (float*)d_out;
    char* ws = (char*)d_ws;

    u16*    Xsw      = (u16*)d_out;          // 32 MiB scratch in d_out (overwritten by rescore)
    float4* top2     = (float4*)(ws + P_TOP2);
    u16*    Esw      = (u16*)(ws + P_ESW);
    u16*    Eext     = (u16*)(ws + P_EXT);
    double* partials = (double*)(ws + P_PART);

    xconv_kernel<<<(B_N * 32) / 256, 256, 0, stream>>>(X, Xsw);
    econv_kernel<<<(K_N * 32) / 256, 256, 0, stream>>>(E, Esw);
    en2ext_kernel<<<(K_N * 64) / 256, 256, 0, stream>>>(E, Eext);
    dist4_kernel<<<dim3(B_N / 128, NCH), 256, 0, stream>>>(
        (const char*)Xsw, (const char*)Esw, (const char*)Eext, top2);
    rescore_kernel<<<512, 256, 0, stream>>>(X, E, top2, out, partials);
    finalize_kernel<<<1, 256, 0, stream>>>(partials, 512, out + (size_t)B_N * D_N);
}

// Round 5
// 284.246 us; speedup vs baseline: 1.2554x; 1.2554x over previous
//
#include <hip/hip_runtime.h>
#include <hip/hip_bf16.h>

// VQ-VAE vector quantizer: B=32768, K=4096, D=256 (fp32)
// out = [quantized (B*D floats), vq_loss (1 float)]
//
//  xconv : X -> fp16 hi/lo, swizzled into d_out (32MB, overwritten later by rescore)
//  econv : E -> NEGATED fp16 (hi only), swizzled into ws
//  en2   : en2f[k] = 0.5*||E_k||^2 exact fp32 into ws
//  dist5 : plain GEMM over virtual K=512 ([Xh|Xl]x[-Eh|-Eh]), 4-buffer 3-deep
//          counted-vmcnt pipeline, 128 uniform phases; epilogue per 128-code
//          subtile: v = en2 + acc, per-row top-2 per 1024-code chunk
//  rescore: fp64 rescore of 8 candidates -> exact winner, gather, loss partials
//  finalize: loss = 1.25 * mean((x-q)^2)

#define B_N 32768
#define K_N 4096
#define D_N 256
#define NCH 4

typedef _Float16 f16x8 __attribute__((ext_vector_type(8)));
typedef float f32x4 __attribute__((ext_vector_type(4)));
typedef unsigned int uint4v __attribute__((ext_vector_type(4)));
typedef unsigned short u16;

// ws layout (~4 MB; ws proven >= 6.3 MB in R3)
static constexpr size_t P_TOP2 = 0;                                  // 32768*4*16 = 2 MB
static constexpr size_t P_ESW  = (size_t)B_N * NCH * 16;             // +2 MB
static constexpr size_t P_EN2  = P_ESW + (size_t)K_N * D_N * 2;      // +16 KB
static constexpr size_t P_PART = P_EN2 + (size_t)K_N * 4;            // +4 KB

__device__ __forceinline__ u16 f2h(float f) {
    _Float16 h = (_Float16)f;
    return __builtin_bit_cast(u16, h);
}
__device__ __forceinline__ float h2f(u16 u) {
    return (float)__builtin_bit_cast(_Float16, u);
}

__device__ __forceinline__ void gload_lds16(const void* g, void* l) {
    __builtin_amdgcn_global_load_lds(
        (const __attribute__((address_space(1))) void*)g,
        (__attribute__((address_space(3))) void*)l, 16, 0, 0);
}

#define WAITVM(N) asm volatile("s_waitcnt vmcnt(" #N ")" ::: "memory")
#define BARRIER() __builtin_amdgcn_s_barrier()

__device__ __forceinline__ void top2_merge(float& v0, int& i0, float& v1, int& i1,
                                           float ov0, int oi0, float ov1, int oi1) {
    bool bf_ = (ov0 < v0) || (ov0 == v0 && oi0 < i0);
    float w0v = bf_ ? ov0 : v0;  int w0i = bf_ ? oi0 : i0;
    float lv  = bf_ ? v0  : ov0; int li  = bf_ ? i0  : oi0;
    float cv  = bf_ ? ov1 : v1;  int ci  = bf_ ? oi1 : i1;
    bool tl = (lv < cv) || (lv == cv && li < ci);
    v0 = w0v; i0 = w0i;
    v1 = tl ? lv : cv; i1 = tl ? li : ci;
}

// ---------- xconv: X -> fp16 hi/lo swizzled ----------
// byte off = ((rb*2+term)*8 + kb)*8192 + rf*1024 + lane*16
// row = rb*128 + rf*16 + llo ; d = kb*32 + lhi*8 + j ; lane = lhi*16+llo
__global__ void xconv_kernel(const float* __restrict__ X, u16* __restrict__ Xsw) {
    const int gid = blockIdx.x * 256 + threadIdx.x;     // B_N*32 threads
    const int row = gid >> 5;
    const int d0  = (gid & 31) << 3;
    const float4 a = *reinterpret_cast<const float4*>(X + (size_t)row * D_N + d0);
    const float4 b = *reinterpret_cast<const float4*>(X + (size_t)row * D_N + d0 + 4);
    float f[8] = {a.x, a.y, a.z, a.w, b.x, b.y, b.z, b.w};
    unsigned hi[8], lo[8];
    #pragma unroll
    for (int j = 0; j < 8; ++j) {
        hi[j] = f2h(f[j]);
        lo[j] = f2h(f[j] - h2f((u16)hi[j]));
    }
    const int rb = row >> 7, rr = row & 127, rf = rr >> 4, llo = rr & 15;
    const int kb = d0 >> 5, lhi = (d0 & 31) >> 3, lane = lhi * 16 + llo;
    // u16 index = ((rb*2+term)*8 + kb)*4096 + rf*512 + lane*8
    size_t base = ((size_t)(rb * 2) * 8 + kb) * 4096 + (size_t)rf * 512 + (size_t)lane * 8;
    uint4v hv, lv;
    hv.x = hi[0] | (hi[1] << 16); hv.y = hi[2] | (hi[3] << 16);
    hv.z = hi[4] | (hi[5] << 16); hv.w = hi[6] | (hi[7] << 16);
    lv.x = lo[0] | (lo[1] << 16); lv.y = lo[2] | (lo[3] << 16);
    lv.z = lo[4] | (lo[5] << 16); lv.w = lo[6] | (lo[7] << 16);
    *reinterpret_cast<uint4v*>(Xsw + base) = hv;
    *reinterpret_cast<uint4v*>(Xsw + base + 8 * 4096) = lv;   // term stride = 8 kb * 4096 u16
}

// ---------- econv: E -> negated fp16 hi, swizzled ----------
// u16 index = ((chunk*8+cb)*8 + kb)*4096 + cf*512 + lane*8
__global__ void econv_kernel(const float* __restrict__ E, u16* __restrict__ Esw) {
    const int gid = blockIdx.x * 256 + threadIdx.x;     // K_N*32 threads
    const int code = gid >> 5;
    const int d0  = (gid & 31) << 3;
    const float4 a = *reinterpret_cast<const float4*>(E + (size_t)code * D_N + d0);
    const float4 b = *reinterpret_cast<const float4*>(E + (size_t)code * D_N + d0 + 4);
    float f[8] = {a.x, a.y, a.z, a.w, b.x, b.y, b.z, b.w};
    unsigned hi[8];
    #pragma unroll
    for (int j = 0; j < 8; ++j) hi[j] = f2h(-f[j]);
    const int chunk = code >> 10, cb = (code >> 7) & 7, c2 = code & 127;
    const int cf = c2 >> 4, llo = c2 & 15;
    const int kb = d0 >> 5, lhi = (d0 & 31) >> 3, lane = lhi * 16 + llo;
    size_t base = ((size_t)(chunk * 8 + cb) * 8 + kb) * 4096 + (size_t)cf * 512 + (size_t)lane * 8;
    uint4v hv;
    hv.x = hi[0] | (hi[1] << 16); hv.y = hi[2] | (hi[3] << 16);
    hv.z = hi[4] | (hi[5] << 16); hv.w = hi[6] | (hi[7] << 16);
    *reinterpret_cast<uint4v*>(Esw + base) = hv;
}

// ---------- en2: exact fp32 0.5||e||^2 ----------
__global__ void en2_kernel(const float* __restrict__ E, float* __restrict__ en2f) {
    const int gtid = blockIdx.x * blockDim.x + threadIdx.x;
    const int code = gtid >> 6;
    const int lane = threadIdx.x & 63;
    if (code >= K_N) return;
    const float4 v = *reinterpret_cast<const float4*>(E + (size_t)code * D_N + lane * 4);
    double s = (double)v.x * v.x + (double)v.y * v.y + (double)v.z * v.z + (double)v.w * v.w;
    #pragma unroll
    for (int o = 32; o; o >>= 1) s += __shfl_xor(s, o, 64);
    if (lane == 0) en2f[code] = (float)(0.5 * s);
}

// ---------- dist5: uniform-phase pipelined GEMM + top-2 ----------
// 1024 blocks (rb = bid>>2, chunk = bid&3), 256 thr (4 waves 2x2),
// block tile 128 rows x 128 codes, wave tile 64x64, acc[4][4] (64 VGPR).
// 128 phases: ph -> cb=ph>>4, term=(ph>>3)&1, kb=ph&7. Per phase stage 16KB
// (X-term tile 8K + E tile 8K) into buffer ph&3; 3-deep lookahead vmcnt(12).
// LDS: 4 x 16KB bufs + 4KB en2 = 68KB -> 2 blocks/CU.
__launch_bounds__(256, 2)
__global__ void dist5_kernel(const char* __restrict__ Xsw, const char* __restrict__ Esw,
                             const float* __restrict__ en2f, float4* __restrict__ top2) {
    __shared__ __align__(16) char lds[69632];
    const int tid  = threadIdx.x;
    const int lane = tid & 63;
    const int wid  = tid >> 6;
    const int wr   = wid >> 1, wc = wid & 1;
    const int llo  = lane & 15, lhi = lane >> 4;
    const int rb    = blockIdx.x >> 2;
    const int chunk = blockIdx.x & 3;

    const char* xb = Xsw + (size_t)rb * 131072;       // 2 terms x 8 kb x 8KB
    const char* eb = Esw + (size_t)chunk * 524288;    // 8 cb x 8 kb x 8KB

    float tv0[16], tv1[16];
    int   tpk[16];
    #pragma unroll
    for (int s = 0; s < 16; ++s) { tv0[s] = 3.4e38f; tv1[s] = 3.4e38f; tpk[s] = -1; }

    f32x4 acc[4][4];
    #pragma unroll
    for (int i = 0; i < 4; ++i)
        #pragma unroll
        for (int j = 0; j < 4; ++j) acc[i][j] = (f32x4){0.f, 0.f, 0.f, 0.f};

    auto STAGE = [&](int ph) {
        const int cb = ph >> 4, t = (ph >> 3) & 1, kb = ph & 7, b = ph & 3;
        const char* xs = xb + (size_t)(t * 8 + kb) * 8192;
        const char* es = eb + (size_t)(cb * 8 + kb) * 8192;
        char* lb = lds + b * 16384;
        gload_lds16(xs + wid * 2048 + lane * 16,        lb + wid * 2048);
        gload_lds16(xs + wid * 2048 + 1024 + lane * 16, lb + wid * 2048 + 1024);
        gload_lds16(es + wid * 2048 + lane * 16,        lb + 8192 + wid * 2048);
        gload_lds16(es + wid * 2048 + 1024 + lane * 16, lb + 8192 + wid * 2048 + 1024);
    };

    // prologue: stage ph 0..2 + en2 slice, drain once
    STAGE(0); STAGE(1); STAGE(2);
    gload_lds16((const char*)en2f + chunk * 4096 + tid * 16, lds + 65536 + wid * 1024);
    WAITVM(0);
    BARRIER();

    for (int ph = 0; ph < 128; ++ph) {
        if (ph < 125)       { STAGE(ph + 3); WAITVM(12); }
        else if (ph == 125) { WAITVM(8); }
        else if (ph == 126) { WAITVM(4); }
        else                { WAITVM(0); }
        BARRIER();

        const f16x8* LA = reinterpret_cast<const f16x8*>(lds + (ph & 3) * 16384);
        const f16x8* LB = reinterpret_cast<const f16x8*>(lds + (ph & 3) * 16384 + 8192);
        f16x8 av[4], bv[4];
        #pragma unroll
        for (int i = 0; i < 4; ++i) av[i] = LA[(wr * 4 + i) * 64 + lane];
        #pragma unroll
        for (int j = 0; j < 4; ++j) bv[j] = LB[(wc * 4 + j) * 64 + lane];

        __builtin_amdgcn_s_setprio(1);
        #pragma unroll
        for (int i = 0; i < 4; ++i)
            #pragma unroll
            for (int j = 0; j < 4; ++j)
                acc[i][j] = __builtin_amdgcn_mfma_f32_16x16x32_f16(av[i], bv[j], acc[i][j], 0, 0, 0);
        __builtin_amdgcn_s_setprio(0);

        if ((ph & 15) == 15) {
            // cb complete: v = 0.5||e||^2 - x.e ; update per-lane top-2
            const int cb = ph >> 4;
            const int codebase = chunk * 1024 + cb * 128;
            #pragma unroll
            for (int j = 0; j < 4; ++j) {
                const int cj = (wc * 4 + j) * 16 + llo;
                const float en = *reinterpret_cast<const float*>(
                    lds + 65536 + (size_t)(cb * 128 + cj) * 4);
                const int idx = codebase + cj;
                #pragma unroll
                for (int i = 0; i < 4; ++i) {
                    #pragma unroll
                    for (int r = 0; r < 4; ++r) {
                        const float v = en + acc[i][j][r];
                        const int s = i * 4 + r;
                        const bool c0 = v < tv0[s];
                        const bool c1 = v < tv1[s];
                        const int pk = tpk[s];
                        const int pkA = (pk << 16) | idx;
                        const int pkB = (idx << 16) | (pk & 0xffff);
                        tv1[s] = c0 ? tv0[s] : (c1 ? v : tv1[s]);
                        tv0[s] = c0 ? v : tv0[s];
                        tpk[s] = c0 ? pkA : (c1 ? pkB : pk);
                    }
                }
            }
            #pragma unroll
            for (int i = 0; i < 4; ++i)
                #pragma unroll
                for (int j = 0; j < 4; ++j) acc[i][j] = (f32x4){0.f, 0.f, 0.f, 0.f};
        }
        BARRIER();
    }

    // cross-lane butterfly merge over the 16 column-lanes
    #pragma unroll
    for (int m = 1; m <= 8; m <<= 1) {
        #pragma unroll
        for (int s = 0; s < 16; ++s) {
            float ov0 = __shfl_xor(tv0[s], m, 64);
            float ov1 = __shfl_xor(tv1[s], m, 64);
            int   opk = __shfl_xor(tpk[s], m, 64);
            float v0 = tv0[s], v1 = tv1[s];
            int i0 = tpk[s] & 0xffff, i1 = (tpk[s] >> 16) & 0xffff;
            top2_merge(v0, i0, v1, i1, ov0, opk & 0xffff, ov1, (opk >> 16) & 0xffff);
            tv0[s] = v0; tv1[s] = v1; tpk[s] = (i1 << 16) | i0;
        }
    }

    __syncthreads();
    float4* M = reinterpret_cast<float4*>(lds);   // [128][2]
    if (llo == 0) {
        #pragma unroll
        for (int i = 0; i < 4; ++i)
            #pragma unroll
            for (int r = 0; r < 4; ++r) {
                const int rowl = wr * 64 + i * 16 + lhi * 4 + r;
                const int s = i * 4 + r;
                M[rowl * 2 + wc] = make_float4(tv0[s], __int_as_float(tpk[s] & 0xffff),
                                               tv1[s], __int_as_float((tpk[s] >> 16) & 0xffff));
            }
    }
    __syncthreads();
    if (tid < 128) {
        float4 A4 = M[tid * 2 + 0], B4 = M[tid * 2 + 1];
        float v0 = A4.x, v1 = A4.z;
        int i0 = __float_as_int(A4.y), i1 = __float_as_int(A4.w);
        top2_merge(v0, i0, v1, i1, B4.x, __float_as_int(B4.y), B4.z, __float_as_int(B4.w));
        top2[(size_t)(rb * 128 + tid) * NCH + chunk] =
            make_float4(v0, __int_as_float(i0), v1, __int_as_float(i1));
    }
}

// ---------- rescore: fp64 rescore of 8 candidates ----------
__global__ void rescore_kernel(const float* __restrict__ X, const float* __restrict__ E,
                               const float4* __restrict__ top2, float* __restrict__ out,
                               double* __restrict__ partials) {
    const int lane = threadIdx.x & 63;
    const int wid  = (blockIdx.x * blockDim.x + threadIdx.x) >> 6;
    const int nw   = (gridDim.x * blockDim.x) >> 6;
    double wloc = 0.0;

    for (int row = wid; row < B_N; row += nw) {
        int cand[8];
        #pragma unroll
        for (int c = 0; c < 4; ++c) {
            float4 t = top2[(size_t)row * NCH + c];
            cand[2 * c]     = __float_as_int(t.y);
            cand[2 * c + 1] = __float_as_int(t.w);
        }
        const float4 xv = *reinterpret_cast<const float4*>(X + (size_t)row * D_N + lane * 4);

        double bestd = 1e300; int besti = 0x7fffffff;
        float4 beste = make_float4(0.f, 0.f, 0.f, 0.f);
        #pragma unroll
        for (int c = 0; c < 8; ++c) {
            const int k = cand[c];
            const float4 ev = *reinterpret_cast<const float4*>(E + (size_t)k * D_N + lane * 4);
            double dx = (double)xv.x - (double)ev.x;
            double dy = (double)xv.y - (double)ev.y;
            double dz = (double)xv.z - (double)ev.z;
            double dw = (double)xv.w - (double)ev.w;
            double s = dx * dx + dy * dy + dz * dz + dw * dw;
            #pragma unroll
            for (int o = 32; o; o >>= 1) s += __shfl_xor(s, o, 64);
            if (s < bestd || (s == bestd && k < besti)) { bestd = s; besti = k; beste = ev; }
        }
        *reinterpret_cast<float4*>(out + (size_t)row * D_N + lane * 4) = beste;
        wloc += bestd;
    }

    __shared__ double bsum[8];
    const int widx = threadIdx.x >> 6;
    if (lane == 0) bsum[widx] = wloc;
    __syncthreads();
    if (threadIdx.x == 0) {
        double s = 0.0;
        for (int w = 0; w < (int)(blockDim.x >> 6); ++w) s += bsum[w];
        partials[blockIdx.x] = s;
    }
}

__global__ void finalize_kernel(const double* __restrict__ partials, int n,
                                float* __restrict__ loss_out) {
    __shared__ double sm[256];
    double s = 0.0;
    for (int i = threadIdx.x; i < n; i += 256) s += partials[i];
    sm[threadIdx.x] = s;
    __syncthreads();
    for (int st = 128; st; st >>= 1) {
        if (threadIdx.x < st) sm[threadIdx.x] += sm[threadIdx.x + st];
        __syncthreads();
    }
    if (threadIdx.x == 0)
        *loss_out = (float)(1.25 * sm[0] / (double)((size_t)B_N * D_N));
}

extern "C" void kernel_launch(void* const* d_in, const int* in_sizes, int n_in,
                              void* d_out, int out_size, void* d_ws, size_t ws_size,
                              hipStream_t stream) {
    const float* X = (const float*)d_in[0];
    const float* E = (const float*)d_in[1];
    float* out = (float*)d_out;
    char* ws = (char*)d_ws;

    u16*    Xsw      = (u16*)d_out;          // 32 MiB scratch in d_out (overwritten by rescore)
    float4* top2     = (float4*)(ws + P_TOP2);
    u16*    Esw      = (u16*)(ws + P_ESW);
    float*  en2f     = (float*)(ws + P_EN2);
    double* partials = (double*)(ws + P_PART);

    xconv_kernel<<<(B_N * 32) / 256, 256, 0, stream>>>(X, Xsw);
    econv_kernel<<<(K_N * 32) / 256, 256, 0, stream>>>(E, Esw);
    en2_kernel<<<K_N / 4, 256, 0, stream>>>(E, en2f);
    dist5_kernel<<<B_N / 128 * NCH, 256, 0, stream>>>(
        (const char*)Xsw, (const char*)Esw, en2f, top2);
    rescore_kernel<<<512, 256, 0, stream>>>(X, E, top2, out, partials);
    finalize_kernel<<<1, 256, 0, stream>>>(partials, 512, out + (size_t)B_N * D_N);
}

// Round 6
// 186.906 us; speedup vs baseline: 1.9092x; 1.5208x over previous
//
#include <hip/hip_runtime.h>

// VQ-VAE vector quantizer: B=32768, K=4096, D=256 (fp32)
// out = [quantized (B*D floats), vq_loss (1 float)]
//
//  xconv : X -> fp16 hi/lo, swizzled into d_out (32MB, overwritten later by rescore)
//  econv : E -> NEGATED fp16 (hi only), tiled [ct(16)][kb(8)] 16KB frag tiles in ws
//  en2   : en2f[k] = 0.5*||E_k||^2 exact fp32 into ws
//  dist6 : X-resident-in-LDS GEMM. Block = 128 rows x ALL 4096 codes.
//          X (128KB fp16 hi+lo, virtual K=512) loaded to LDS once; loop stages only
//          E tiles (16KB, double-buffered, counted vmcnt(2)). 128 phases
//          (16 ctiles x 8 kb), 32 MFMA/wave/phase. v = 0.5||e||^2 - x.e,
//          single-pass per-row top-2 over all codes.
//  rescore: fp64 rescore of 2 candidates -> exact winner, gather, loss partials
//  finalize: loss = 1.25 * mean((x-q)^2)

#define B_N 32768
#define K_N 4096
#define D_N 256

typedef _Float16 f16x8 __attribute__((ext_vector_type(8)));
typedef float f32x4 __attribute__((ext_vector_type(4)));
typedef unsigned int uint4v __attribute__((ext_vector_type(4)));
typedef unsigned short u16;

// ws layout (~2.6 MB)
static constexpr size_t P_TOP2 = 0;                               // 32768*16 = 512 KB
static constexpr size_t P_ESW  = (size_t)B_N * 16;                // +2 MB
static constexpr size_t P_EN2  = P_ESW + (size_t)K_N * D_N * 2;   // +16 KB
static constexpr size_t P_PART = P_EN2 + (size_t)K_N * 4;         // +4 KB

__device__ __forceinline__ u16 f2h(float f) {
    _Float16 h = (_Float16)f;
    return __builtin_bit_cast(u16, h);
}
__device__ __forceinline__ float h2f(u16 u) {
    return (float)__builtin_bit_cast(_Float16, u);
}

__device__ __forceinline__ void gload_lds16(const void* g, void* l) {
    __builtin_amdgcn_global_load_lds(
        (const __attribute__((address_space(1))) void*)g,
        (__attribute__((address_space(3))) void*)l, 16, 0, 0);
}

#define WAITVM(N) asm volatile("s_waitcnt vmcnt(" #N ")" ::: "memory")
#define BARRIER() __builtin_amdgcn_s_barrier()

__device__ __forceinline__ void top2_merge(float& v0, int& i0, float& v1, int& i1,
                                           float ov0, int oi0, float ov1, int oi1) {
    bool bf_ = (ov0 < v0) || (ov0 == v0 && oi0 < i0);
    float w0v = bf_ ? ov0 : v0;  int w0i = bf_ ? oi0 : i0;
    float lv  = bf_ ? v0  : ov0; int li  = bf_ ? i0  : oi0;
    float cv  = bf_ ? ov1 : v1;  int ci  = bf_ ? oi1 : i1;
    bool tl = (lv < cv) || (lv == cv && li < ci);
    v0 = w0v; i0 = w0i;
    v1 = tl ? lv : cv; i1 = tl ? li : ci;
}

// ---------- xconv: X -> fp16 hi/lo swizzled (layout matches LDS residency order) ----------
// u16 index = ((rb*2+term)*8 + kb)*4096 + rf*512 + lane*8
// row = rb*128 + rf*16 + llo ; d = kb*32 + lhi*8 + j ; lane = lhi*16+llo
__global__ void xconv_kernel(const float* __restrict__ X, u16* __restrict__ Xsw) {
    const int gid = blockIdx.x * 256 + threadIdx.x;     // B_N*32 threads
    const int row = gid >> 5;
    const int d0  = (gid & 31) << 3;
    const float4 a = *reinterpret_cast<const float4*>(X + (size_t)row * D_N + d0);
    const float4 b = *reinterpret_cast<const float4*>(X + (size_t)row * D_N + d0 + 4);
    float f[8] = {a.x, a.y, a.z, a.w, b.x, b.y, b.z, b.w};
    unsigned hi[8], lo[8];
    #pragma unroll
    for (int j = 0; j < 8; ++j) {
        hi[j] = f2h(f[j]);
        lo[j] = f2h(f[j] - h2f((u16)hi[j]));
    }
    const int rb = row >> 7, rr = row & 127, rf = rr >> 4, llo = rr & 15;
    const int kb = d0 >> 5, lhi = (d0 & 31) >> 3, lane = lhi * 16 + llo;
    size_t base = ((size_t)(rb * 2) * 8 + kb) * 4096 + (size_t)rf * 512 + (size_t)lane * 8;
    uint4v hv, lv;
    hv.x = hi[0] | (hi[1] << 16); hv.y = hi[2] | (hi[3] << 16);
    hv.z = hi[4] | (hi[5] << 16); hv.w = hi[6] | (hi[7] << 16);
    lv.x = lo[0] | (lo[1] << 16); lv.y = lo[2] | (lo[3] << 16);
    lv.z = lo[4] | (lo[5] << 16); lv.w = lo[6] | (lo[7] << 16);
    *reinterpret_cast<uint4v*>(Xsw + base) = hv;
    *reinterpret_cast<uint4v*>(Xsw + base + 8 * 4096) = lv;   // term stride = 8*4096 u16
}

// ---------- econv: E -> negated fp16 hi, tiled [ct][kb] ----------
// u16 index = (ct*8+kb)*8192 + cf*512 + lane*8 ; ct = code>>8, cf = (code>>4)&15
__global__ void econv_kernel(const float* __restrict__ E, u16* __restrict__ Esw) {
    const int gid = blockIdx.x * 256 + threadIdx.x;     // K_N*32 threads
    const int code = gid >> 5;
    const int d0  = (gid & 31) << 3;
    const float4 a = *reinterpret_cast<const float4*>(E + (size_t)code * D_N + d0);
    const float4 b = *reinterpret_cast<const float4*>(E + (size_t)code * D_N + d0 + 4);
    float f[8] = {a.x, a.y, a.z, a.w, b.x, b.y, b.z, b.w};
    unsigned hi[8];
    #pragma unroll
    for (int j = 0; j < 8; ++j) hi[j] = f2h(-f[j]);
    const int ct = code >> 8, cf = (code >> 4) & 15, llo = code & 15;
    const int kb = d0 >> 5, lhi = (d0 & 31) >> 3, lane = lhi * 16 + llo;
    size_t base = (size_t)(ct * 8 + kb) * 8192 + (size_t)cf * 512 + (size_t)lane * 8;
    uint4v hv;
    hv.x = hi[0] | (hi[1] << 16); hv.y = hi[2] | (hi[3] << 16);
    hv.z = hi[4] | (hi[5] << 16); hv.w = hi[6] | (hi[7] << 16);
    *reinterpret_cast<uint4v*>(Esw + base) = hv;
}

// ---------- en2: exact fp32 0.5||e||^2 ----------
__global__ void en2_kernel(const float* __restrict__ E, float* __restrict__ en2f) {
    const int gtid = blockIdx.x * blockDim.x + threadIdx.x;
    const int code = gtid >> 6;
    const int lane = threadIdx.x & 63;
    if (code >= K_N) return;
    const float4 v = *reinterpret_cast<const float4*>(E + (size_t)code * D_N + lane * 4);
    double s = (double)v.x * v.x + (double)v.y * v.y + (double)v.z * v.z + (double)v.w * v.w;
    #pragma unroll
    for (int o = 32; o; o >>= 1) s += __shfl_xor(s, o, 64);
    if (lane == 0) en2f[code] = (float)(0.5 * s);
}

// ---------- dist6: X-resident GEMM + single-pass top-2 ----------
// 256 blocks (1/CU), 512 thr = 8 waves (2 wr x 4 wc), wave tile 64x64.
// LDS: X[term(2)][kb(8)][rf(8)][lane(64)][8] = 128KB @0 ; E dbuf 2x16KB @128K.
__launch_bounds__(512, 1)
__global__ void dist6_kernel(const char* __restrict__ Xsw, const char* __restrict__ Esw,
                             const float* __restrict__ en2f, float4* __restrict__ top2) {
    __shared__ __align__(16) char lds[163840];
    const int tid  = threadIdx.x;
    const int lane = tid & 63;
    const int wid  = tid >> 6;          // 0..7
    const int wr   = wid >> 2;          // 0..1
    const int wc   = wid & 3;           // 0..3
    const int llo  = lane & 15, lhi = lane >> 4;
    const int rb = blockIdx.x;

    const char* xb = Xsw + (size_t)rb * 131072;

    auto STAGE_E = [&](int p) {   // stage E tile p (16KB) into buf p&1
        const char* es = Esw + (size_t)p * 16384;
        char* lb = lds + 131072 + (p & 1) * 16384;
        gload_lds16(es + wid * 1024 + lane * 16,        lb + wid * 1024);
        gload_lds16(es + 8192 + wid * 1024 + lane * 16, lb + 8192 + wid * 1024);
    };

    float tv0[16], tv1[16];
    int   tpk[16];
    #pragma unroll
    for (int s = 0; s < 16; ++s) { tv0[s] = 3.4e38f; tv1[s] = 3.4e38f; tpk[s] = -1; }

    f32x4 acc[4][4];
    #pragma unroll
    for (int i = 0; i < 4; ++i)
        #pragma unroll
        for (int j = 0; j < 4; ++j) acc[i][j] = (f32x4){0.f, 0.f, 0.f, 0.f};

    // prologue: X to LDS (16 x 8KB), E tile 0, en2 for ctile 0
    #pragma unroll
    for (int it = 0; it < 16; ++it)
        gload_lds16(xb + it * 8192 + wid * 1024 + lane * 16, lds + it * 8192 + wid * 1024);
    STAGE_E(0);
    float ena[4], enb[4];
    #pragma unroll
    for (int j = 0; j < 4; ++j) ena[j] = en2f[(wc * 4 + j) * 16 + llo];
    WAITVM(4);   // X + E0 done (ena 4 may fly)
    BARRIER();

    for (int ct = 0; ct < 16; ++ct) {
        #pragma unroll
        for (int kb = 0; kb < 8; ++kb) {
            const int p = ct * 8 + kb;
            if (kb == 6 && ct < 15) {       // prefetch en2 for next ctile (issued first!)
                #pragma unroll
                for (int j = 0; j < 4; ++j)
                    enb[j] = en2f[(ct + 1) * 256 + (wc * 4 + j) * 16 + llo];
            }
            if (p < 127) STAGE_E(p + 1);
            if (p == 127)                  { WAITVM(0); }
            else if (kb == 6 && ct < 15)   { WAITVM(6); }
            else                           { WAITVM(2); }
            BARRIER();

            const f16x8* LX = reinterpret_cast<const f16x8*>(lds);
            const f16x8* LE = reinterpret_cast<const f16x8*>(lds + 131072 + (kb & 1) * 16384);
            f16x8 bv[4];
            #pragma unroll
            for (int j = 0; j < 4; ++j) bv[j] = LE[(wc * 4 + j) * 64 + lane];

            __builtin_amdgcn_s_setprio(1);
            #pragma unroll
            for (int term = 0; term < 2; ++term) {
                f16x8 av[4];
                #pragma unroll
                for (int i = 0; i < 4; ++i)
                    av[i] = LX[((term * 8 + kb) * 8 + wr * 4 + i) * 64 + lane];
                #pragma unroll
                for (int i = 0; i < 4; ++i)
                    #pragma unroll
                    for (int j = 0; j < 4; ++j)
                        acc[i][j] = __builtin_amdgcn_mfma_f32_16x16x32_f16(av[i], bv[j], acc[i][j], 0, 0, 0);
            }
            __builtin_amdgcn_s_setprio(0);
            BARRIER();
        }

        // epilogue for ctile ct: v = 0.5||e||^2 - x.e ; per-lane top-2 update
        #pragma unroll
        for (int j = 0; j < 4; ++j) {
            const int idx = ct * 256 + (wc * 4 + j) * 16 + llo;
            const float en = ena[j];
            #pragma unroll
            for (int i = 0; i < 4; ++i) {
                #pragma unroll
                for (int r = 0; r < 4; ++r) {
                    const float v = en + acc[i][j][r];
                    const int s = i * 4 + r;
                    const bool c0 = v < tv0[s];
                    const bool c1 = v < tv1[s];
                    const int pk = tpk[s];
                    const int pkA = (pk << 16) | idx;
                    const int pkB = (idx << 16) | (pk & 0xffff);
                    tv1[s] = c0 ? tv0[s] : (c1 ? v : tv1[s]);
                    tv0[s] = c0 ? v : tv0[s];
                    tpk[s] = c0 ? pkA : (c1 ? pkB : pk);
                }
            }
        }
        #pragma unroll
        for (int i = 0; i < 4; ++i)
            #pragma unroll
            for (int j = 0; j < 4; ++j) acc[i][j] = (f32x4){0.f, 0.f, 0.f, 0.f};
        if (ct < 15) {
            #pragma unroll
            for (int j = 0; j < 4; ++j) ena[j] = enb[j];
        }
    }

    // merge the 16 column-lanes (llo) via shfl butterfly
    #pragma unroll
    for (int m = 1; m <= 8; m <<= 1) {
        #pragma unroll
        for (int s = 0; s < 16; ++s) {
            float ov0 = __shfl_xor(tv0[s], m, 64);
            float ov1 = __shfl_xor(tv1[s], m, 64);
            int   opk = __shfl_xor(tpk[s], m, 64);
            float v0 = tv0[s], v1 = tv1[s];
            int i0 = tpk[s] & 0xffff, i1 = (tpk[s] >> 16) & 0xffff;
            top2_merge(v0, i0, v1, i1, ov0, opk & 0xffff, ov1, (opk >> 16) & 0xffff);
            tv0[s] = v0; tv1[s] = v1; tpk[s] = (i1 << 16) | i0;
        }
    }

    __syncthreads();
    float4* M = reinterpret_cast<float4*>(lds);   // [128 rows][4 wc] (reuses X region)
    if (llo == 0) {
        #pragma unroll
        for (int i = 0; i < 4; ++i)
            #pragma unroll
            for (int r = 0; r < 4; ++r) {
                const int rowl = wr * 64 + i * 16 + lhi * 4 + r;
                const int s = i * 4 + r;
                M[rowl * 4 + wc] = make_float4(tv0[s], __int_as_float(tpk[s] & 0xffff),
                                               tv1[s], __int_as_float((tpk[s] >> 16) & 0xffff));
            }
    }
    __syncthreads();
    if (tid < 128) {
        float4 A4 = M[tid * 4 + 0];
        float v0 = A4.x, v1 = A4.z;
        int i0 = __float_as_int(A4.y), i1 = __float_as_int(A4.w);
        #pragma unroll
        for (int w = 1; w < 4; ++w) {
            float4 Bw = M[tid * 4 + w];
            top2_merge(v0, i0, v1, i1, Bw.x, __float_as_int(Bw.y), Bw.z, __float_as_int(Bw.w));
        }
        top2[(size_t)(rb * 128 + tid)] =
            make_float4(v0, __int_as_float(i0), v1, __int_as_float(i1));
    }
}

// ---------- rescore: fp64 rescore of 2 candidates ----------
__global__ void rescore_kernel(const float* __restrict__ X, const float* __restrict__ E,
                               const float4* __restrict__ top2, float* __restrict__ out,
                               double* __restrict__ partials) {
    const int lane = threadIdx.x & 63;
    const int wid  = (blockIdx.x * blockDim.x + threadIdx.x) >> 6;
    const int nw   = (gridDim.x * blockDim.x) >> 6;
    double wloc = 0.0;

    for (int row = wid; row < B_N; row += nw) {
        float4 t = top2[row];
        int cand[2] = { __float_as_int(t.y), __float_as_int(t.w) };
        const float4 xv = *reinterpret_cast<const float4*>(X + (size_t)row * D_N + lane * 4);

        double bestd = 1e300; int besti = 0x7fffffff;
        float4 beste = make_float4(0.f, 0.f, 0.f, 0.f);
        #pragma unroll
        for (int c = 0; c < 2; ++c) {
            const int k = cand[c];
            const float4 ev = *reinterpret_cast<const float4*>(E + (size_t)k * D_N + lane * 4);
            double dx = (double)xv.x - (double)ev.x;
            double dy = (double)xv.y - (double)ev.y;
            double dz = (double)xv.z - (double)ev.z;
            double dw = (double)xv.w - (double)ev.w;
            double s = dx * dx + dy * dy + dz * dz + dw * dw;
            #pragma unroll
            for (int o = 32; o; o >>= 1) s += __shfl_xor(s, o, 64);
            if (s < bestd || (s == bestd && k < besti)) { bestd = s; besti = k; beste = ev; }
        }
        *reinterpret_cast<float4*>(out + (size_t)row * D_N + lane * 4) = beste;
        wloc += bestd;
    }

    __shared__ double bsum[8];
    const int widx = threadIdx.x >> 6;
    if (lane == 0) bsum[widx] = wloc;
    __syncthreads();
    if (threadIdx.x == 0) {
        double s = 0.0;
        for (int w = 0; w < (int)(blockDim.x >> 6); ++w) s += bsum[w];
        partials[blockIdx.x] = s;
    }
}

__global__ void finalize_kernel(const double* __restrict__ partials, int n,
                                float* __restrict__ loss_out) {
    __shared__ double sm[256];
    double s = 0.0;
    for (int i = threadIdx.x; i < n; i += 256) s += partials[i];
    sm[threadIdx.x] = s;
    __syncthreads();
    for (int st = 128; st; st >>= 1) {
        if (threadIdx.x < st) sm[threadIdx.x] += sm[threadIdx.x + st];
        __syncthreads();
    }
    if (threadIdx.x == 0)
        *loss_out = (float)(1.25 * sm[0] / (double)((size_t)B_N * D_N));
}

extern "C" void kernel_launch(void* const* d_in, const int* in_sizes, int n_in,
                              void* d_out, int out_size, void* d_ws, size_t ws_size,
                              hipStream_t stream) {
    const float* X = (const float*)d_in[0];
    const float* E = (const float*)d_in[1];
    float* out = (float*)d_out;
    char* ws = (char*)d_ws;

    u16*    Xsw      = (u16*)d_out;          // 32 MiB scratch in d_out (overwritten by rescore)
    float4* top2     = (float4*)(ws + P_TOP2);
    u16*    Esw      = (u16*)(ws + P_ESW);
    float*  en2f     = (float*)(ws + P_EN2);
    double* partials = (double*)(ws + P_PART);

    xconv_kernel<<<(B_N * 32) / 256, 256, 0, stream>>>(X, Xsw);
    econv_kernel<<<(K_N * 32) / 256, 256, 0, stream>>>(E, Esw);
    en2_kernel<<<K_N / 4, 256, 0, stream>>>(E, en2f);
    dist6_kernel<<<B_N / 128, 512, 0, stream>>>(
        (const char*)Xsw, (const char*)Esw, en2f, top2);
    rescore_kernel<<<512, 256, 0, stream>>>(X, E, top2, out, partials);
    finalize_kernel<<<1, 256, 0, stream>>>(partials, 512, out + (size_t)B_N * D_N);
}

// Round 7
// 186.441 us; speedup vs baseline: 1.9140x; 1.0025x over previous
//
#include <hip/hip_runtime.h>

// VQ-VAE vector quantizer: B=32768, K=4096, D=256 (fp32)
// out = [quantized (B*D floats), vq_loss (1 float)]
//
//  xconv : X -> fp16 hi/lo, swizzled per-64-row-block into d_out (32MB, overwritten later)
//  econv : E -> NEGATED fp16 (hi only), tiled [ct(32)][kb(8)] 8KB frag tiles in ws
//  en2   : en2f[k] = 0.5*||E_k||^2 exact fp32 into ws
//  dist7 : X-resident-in-LDS GEMM, TWO blocks per CU (independent barrier groups).
//          Block = 64 rows x ALL 4096 codes, 256 thr / 4 waves (2x2), wave tile 32x64.
//          X (64KB fp16 hi+lo, virtual K=512) loaded to LDS once; loop stages only
//          E tiles (8KB, double-buffered, counted vmcnt). 256 phases (32 ct x 8 kb).
//          v = 0.5||e||^2 - x.e ; single-pass per-row top-2 over all 4096 codes.
//  rescore: fp64 rescore of 2 candidates -> exact winner, gather, loss partials
//  finalize: loss = 1.25 * mean((x-q)^2)

#define B_N 32768
#define K_N 4096
#define D_N 256

typedef _Float16 f16x8 __attribute__((ext_vector_type(8)));
typedef float f32x4 __attribute__((ext_vector_type(4)));
typedef unsigned int uint4v __attribute__((ext_vector_type(4)));
typedef unsigned short u16;

// ws layout (~2.6 MB)
static constexpr size_t P_TOP2 = 0;                               // 32768*16 = 512 KB
static constexpr size_t P_ESW  = (size_t)B_N * 16;                // +2 MB
static constexpr size_t P_EN2  = P_ESW + (size_t)K_N * D_N * 2;   // +16 KB
static constexpr size_t P_PART = P_EN2 + (size_t)K_N * 4;         // +4 KB

__device__ __forceinline__ u16 f2h(float f) {
    _Float16 h = (_Float16)f;
    return __builtin_bit_cast(u16, h);
}
__device__ __forceinline__ float h2f(u16 u) {
    return (float)__builtin_bit_cast(_Float16, u);
}

__device__ __forceinline__ void gload_lds16(const void* g, void* l) {
    __builtin_amdgcn_global_load_lds(
        (const __attribute__((address_space(1))) void*)g,
        (__attribute__((address_space(3))) void*)l, 16, 0, 0);
}

#define WAITVM(N) asm volatile("s_waitcnt vmcnt(" #N ")" ::: "memory")
#define BARRIER() __builtin_amdgcn_s_barrier()

__device__ __forceinline__ void top2_merge(float& v0, int& i0, float& v1, int& i1,
                                           float ov0, int oi0, float ov1, int oi1) {
    bool bf_ = (ov0 < v0) || (ov0 == v0 && oi0 < i0);
    float w0v = bf_ ? ov0 : v0;  int w0i = bf_ ? oi0 : i0;
    float lv  = bf_ ? v0  : ov0; int li  = bf_ ? i0  : oi0;
    float cv  = bf_ ? ov1 : v1;  int ci  = bf_ ? oi1 : i1;
    bool tl = (lv < cv) || (lv == cv && li < ci);
    v0 = w0v; i0 = w0i;
    v1 = tl ? lv : cv; i1 = tl ? li : ci;
}

// ---------- xconv: X -> fp16 hi/lo, 64-row-block tiles ----------
// u16 index = rb*32768 + (term*8 + kb)*2048 + rf*512 + lane*8
// row = rb*64 + rf*16 + llo ; d = kb*32 + lhi*8 + j ; lane = lhi*16+llo
__global__ void xconv_kernel(const float* __restrict__ X, u16* __restrict__ Xsw) {
    const int gid = blockIdx.x * 256 + threadIdx.x;     // B_N*32 threads
    const int row = gid >> 5;
    const int d0  = (gid & 31) << 3;
    const float4 a = *reinterpret_cast<const float4*>(X + (size_t)row * D_N + d0);
    const float4 b = *reinterpret_cast<const float4*>(X + (size_t)row * D_N + d0 + 4);
    float f[8] = {a.x, a.y, a.z, a.w, b.x, b.y, b.z, b.w};
    unsigned hi[8], lo[8];
    #pragma unroll
    for (int j = 0; j < 8; ++j) {
        hi[j] = f2h(f[j]);
        lo[j] = f2h(f[j] - h2f((u16)hi[j]));
    }
    const int rb = row >> 6, rr = row & 63, rf = rr >> 4, llo = rr & 15;
    const int kb = d0 >> 5, lhi = (d0 & 31) >> 3, lane = lhi * 16 + llo;
    size_t base = (size_t)rb * 32768 + (size_t)kb * 2048 + (size_t)rf * 512 + (size_t)lane * 8;
    uint4v hv, lv;
    hv.x = hi[0] | (hi[1] << 16); hv.y = hi[2] | (hi[3] << 16);
    hv.z = hi[4] | (hi[5] << 16); hv.w = hi[6] | (hi[7] << 16);
    lv.x = lo[0] | (lo[1] << 16); lv.y = lo[2] | (lo[3] << 16);
    lv.z = lo[4] | (lo[5] << 16); lv.w = lo[6] | (lo[7] << 16);
    *reinterpret_cast<uint4v*>(Xsw + base) = hv;
    *reinterpret_cast<uint4v*>(Xsw + base + 16384) = lv;   // term stride = 8*2048 u16
}

// ---------- econv: E -> negated fp16 hi, tiled [ct(32)][kb(8)] 8KB tiles ----------
// u16 index = (ct*8+kb)*4096 + cf*512 + lane*8 ; ct = code>>7, cf = (code>>4)&7
__global__ void econv_kernel(const float* __restrict__ E, u16* __restrict__ Esw) {
    const int gid = blockIdx.x * 256 + threadIdx.x;     // K_N*32 threads
    const int code = gid >> 5;
    const int d0  = (gid & 31) << 3;
    const float4 a = *reinterpret_cast<const float4*>(E + (size_t)code * D_N + d0);
    const float4 b = *reinterpret_cast<const float4*>(E + (size_t)code * D_N + d0 + 4);
    float f[8] = {a.x, a.y, a.z, a.w, b.x, b.y, b.z, b.w};
    unsigned hi[8];
    #pragma unroll
    for (int j = 0; j < 8; ++j) hi[j] = f2h(-f[j]);
    const int ct = code >> 7, cf = (code >> 4) & 7, llo = code & 15;
    const int kb = d0 >> 5, lhi = (d0 & 31) >> 3, lane = lhi * 16 + llo;
    size_t base = (size_t)(ct * 8 + kb) * 4096 + (size_t)cf * 512 + (size_t)lane * 8;
    uint4v hv;
    hv.x = hi[0] | (hi[1] << 16); hv.y = hi[2] | (hi[3] << 16);
    hv.z = hi[4] | (hi[5] << 16); hv.w = hi[6] | (hi[7] << 16);
    *reinterpret_cast<uint4v*>(Esw + base) = hv;
}

// ---------- en2: exact fp32 0.5||e||^2 ----------
__global__ void en2_kernel(const float* __restrict__ E, float* __restrict__ en2f) {
    const int gtid = blockIdx.x * blockDim.x + threadIdx.x;
    const int code = gtid >> 6;
    const int lane = threadIdx.x & 63;
    if (code >= K_N) return;
    const float4 v = *reinterpret_cast<const float4*>(E + (size_t)code * D_N + lane * 4);
    double s = (double)v.x * v.x + (double)v.y * v.y + (double)v.z * v.z + (double)v.w * v.w;
    #pragma unroll
    for (int o = 32; o; o >>= 1) s += __shfl_xor(s, o, 64);
    if (lane == 0) en2f[code] = (float)(0.5 * s);
}

// ---------- dist7: X-resident GEMM, 2 blocks/CU ----------
// 512 blocks, 256 thr = 4 waves (wr=wid>>1, wc=wid&1), wave tile 32 rows x 64 codes.
// LDS 81920 B: X[term2][kb8][rf4][lane64][8]u16 = 64KB @0 ; E dbuf 2x8KB @65536.
__launch_bounds__(256, 2)
__global__ void dist7_kernel(const char* __restrict__ Xsw, const char* __restrict__ Esw,
                             const float* __restrict__ en2f, float4* __restrict__ top2) {
    __shared__ __align__(16) char lds[81920];
    const int tid  = threadIdx.x;
    const int lane = tid & 63;
    const int wid  = tid >> 6;          // 0..3
    const int wr   = wid >> 1;          // 0..1 (row half)
    const int wc   = wid & 1;           // 0..1 (code half)
    const int llo  = lane & 15, lhi = lane >> 4;
    const int rb = blockIdx.x;          // 0..511 (64-row group)

    const char* xb = Xsw + (size_t)rb * 65536;

    auto STAGE_E = [&](int p) {   // stage E tile p (8KB) into buf p&1
        const char* es = Esw + (size_t)p * 8192;
        char* lb = lds + 65536 + (p & 1) * 8192;
        gload_lds16(es + wid * 2048 + lane * 16,        lb + wid * 2048);
        gload_lds16(es + wid * 2048 + 1024 + lane * 16, lb + wid * 2048 + 1024);
    };

    float tv0[8], tv1[8];
    int   tpk[8];
    #pragma unroll
    for (int s = 0; s < 8; ++s) { tv0[s] = 3.4e38f; tv1[s] = 3.4e38f; tpk[s] = -1; }

    f32x4 acc[2][4];
    #pragma unroll
    for (int i = 0; i < 2; ++i)
        #pragma unroll
        for (int j = 0; j < 4; ++j) acc[i][j] = (f32x4){0.f, 0.f, 0.f, 0.f};

    // prologue: X to LDS (64KB = 16 x 4KB), E tile 0, en2 for ctile 0
    #pragma unroll
    for (int it = 0; it < 16; ++it)
        gload_lds16(xb + it * 4096 + tid * 16, lds + it * 4096 + wid * 1024);
    STAGE_E(0);
    float ena[4], enb[4];
    #pragma unroll
    for (int j = 0; j < 4; ++j) ena[j] = en2f[(wc * 4 + j) * 16 + llo];
    WAITVM(0);
    BARRIER();

    for (int ct = 0; ct < 32; ++ct) {
        #pragma unroll
        for (int kb = 0; kb < 8; ++kb) {
            const int p = ct * 8 + kb;
            if (kb == 6 && ct < 31) {        // prefetch next ctile's en2 (flies with stages)
                #pragma unroll
                for (int j = 0; j < 4; ++j)
                    enb[j] = en2f[(ct + 1) * 128 + (wc * 4 + j) * 16 + llo];
            }
            if (p < 255) STAGE_E(p + 1);
            if (p == 255)                 { WAITVM(0); }
            else if (kb == 6 && ct < 31)  { WAITVM(6); }
            else                          { WAITVM(2); }
            BARRIER();

            const f16x8* LX = reinterpret_cast<const f16x8*>(lds);
            const f16x8* LE = reinterpret_cast<const f16x8*>(lds + 65536 + (kb & 1) * 8192);
            f16x8 bv[4];
            #pragma unroll
            for (int j = 0; j < 4; ++j) bv[j] = LE[(wc * 4 + j) * 64 + lane];

            __builtin_amdgcn_s_setprio(1);
            #pragma unroll
            for (int term = 0; term < 2; ++term) {
                f16x8 av[2];
                #pragma unroll
                for (int i = 0; i < 2; ++i)
                    av[i] = LX[((term * 8 + kb) * 4 + wr * 2 + i) * 64 + lane];
                #pragma unroll
                for (int i = 0; i < 2; ++i)
                    #pragma unroll
                    for (int j = 0; j < 4; ++j)
                        acc[i][j] = __builtin_amdgcn_mfma_f32_16x16x32_f16(av[i], bv[j], acc[i][j], 0, 0, 0);
            }
            __builtin_amdgcn_s_setprio(0);

            if (kb == 7) {
                // epilogue for ctile ct: v = 0.5||e||^2 - x.e ; per-lane top-2 update
                #pragma unroll
                for (int j = 0; j < 4; ++j) {
                    const int idx = ct * 128 + (wc * 4 + j) * 16 + llo;
                    const float en = ena[j];
                    #pragma unroll
                    for (int i = 0; i < 2; ++i) {
                        #pragma unroll
                        for (int r = 0; r < 4; ++r) {
                            const float v = en + acc[i][j][r];
                            const int s = i * 4 + r;
                            const bool c0 = v < tv0[s];
                            const bool c1 = v < tv1[s];
                            const int pk = tpk[s];
                            const int pkA = (pk << 16) | idx;
                            const int pkB = (idx << 16) | (pk & 0xffff);
                            tv1[s] = c0 ? tv0[s] : (c1 ? v : tv1[s]);
                            tv0[s] = c0 ? v : tv0[s];
                            tpk[s] = c0 ? pkA : (c1 ? pkB : pk);
                        }
                    }
                }
                #pragma unroll
                for (int i = 0; i < 2; ++i)
                    #pragma unroll
                    for (int j = 0; j < 4; ++j) acc[i][j] = (f32x4){0.f, 0.f, 0.f, 0.f};
                #pragma unroll
                for (int j = 0; j < 4; ++j) ena[j] = enb[j];
            }
            BARRIER();
        }
    }

    // merge the 16 column-lanes (llo) via shfl butterfly
    #pragma unroll
    for (int m = 1; m <= 8; m <<= 1) {
        #pragma unroll
        for (int s = 0; s < 8; ++s) {
            float ov0 = __shfl_xor(tv0[s], m, 64);
            float ov1 = __shfl_xor(tv1[s], m, 64);
            int   opk = __shfl_xor(tpk[s], m, 64);
            float v0 = tv0[s], v1 = tv1[s];
            int i0 = tpk[s] & 0xffff, i1 = (tpk[s] >> 16) & 0xffff;
            top2_merge(v0, i0, v1, i1, ov0, opk & 0xffff, ov1, (opk >> 16) & 0xffff);
            tv0[s] = v0; tv1[s] = v1; tpk[s] = (i1 << 16) | i0;
        }
    }

    __syncthreads();
    float4* M = reinterpret_cast<float4*>(lds);   // [64 rows][2 wc] (reuses X region)
    if (llo == 0) {
        #pragma unroll
        for (int i = 0; i < 2; ++i)
            #pragma unroll
            for (int r = 0; r < 4; ++r) {
                const int rowl = wr * 32 + i * 16 + lhi * 4 + r;
                const int s = i * 4 + r;
                M[rowl * 2 + wc] = make_float4(tv0[s], __int_as_float(tpk[s] & 0xffff),
                                               tv1[s], __int_as_float((tpk[s] >> 16) & 0xffff));
            }
    }
    __syncthreads();
    if (tid < 64) {
        float4 A4 = M[tid * 2 + 0], B4 = M[tid * 2 + 1];
        float v0 = A4.x, v1 = A4.z;
        int i0 = __float_as_int(A4.y), i1 = __float_as_int(A4.w);
        top2_merge(v0, i0, v1, i1, B4.x, __float_as_int(B4.y), B4.z, __float_as_int(B4.w));
        top2[(size_t)(rb * 64 + tid)] =
            make_float4(v0, __int_as_float(i0), v1, __int_as_float(i1));
    }
}

// ---------- rescore: fp64 rescore of 2 candidates ----------
__global__ void rescore_kernel(const float* __restrict__ X, const float* __restrict__ E,
                               const float4* __restrict__ top2, float* __restrict__ out,
                               double* __restrict__ partials) {
    const int lane = threadIdx.x & 63;
    const int wid  = (blockIdx.x * blockDim.x + threadIdx.x) >> 6;
    const int nw   = (gridDim.x * blockDim.x) >> 6;
    double wloc = 0.0;

    for (int row = wid; row < B_N; row += nw) {
        float4 t = top2[row];
        int cand[2] = { __float_as_int(t.y), __float_as_int(t.w) };
        const float4 xv = *reinterpret_cast<const float4*>(X + (size_t)row * D_N + lane * 4);

        double bestd = 1e300; int besti = 0x7fffffff;
        float4 beste = make_float4(0.f, 0.f, 0.f, 0.f);
        #pragma unroll
        for (int c = 0; c < 2; ++c) {
            const int k = cand[c];
            const float4 ev = *reinterpret_cast<const float4*>(E + (size_t)k * D_N + lane * 4);
            double dx = (double)xv.x - (double)ev.x;
            double dy = (double)xv.y - (double)ev.y;
            double dz = (double)xv.z - (double)ev.z;
            double dw = (double)xv.w - (double)ev.w;
            double s = dx * dx + dy * dy + dz * dz + dw * dw;
            #pragma unroll
            for (int o = 32; o; o >>= 1) s += __shfl_xor(s, o, 64);
            if (s < bestd || (s == bestd && k < besti)) { bestd = s; besti = k; beste = ev; }
        }
        *reinterpret_cast<float4*>(out + (size_t)row * D_N + lane * 4) = beste;
        wloc += bestd;
    }

    __shared__ double bsum[8];
    const int widx = threadIdx.x >> 6;
    if (lane == 0) bsum[widx] = wloc;
    __syncthreads();
    if (threadIdx.x == 0) {
        double s = 0.0;
        for (int w = 0; w < (int)(blockDim.x >> 6); ++w) s += bsum[w];
        partials[blockIdx.x] = s;
    }
}

__global__ void finalize_kernel(const double* __restrict__ partials, int n,
                                float* __restrict__ loss_out) {
    __shared__ double sm[256];
    double s = 0.0;
    for (int i = threadIdx.x; i < n; i += 256) s += partials[i];
    sm[threadIdx.x] = s;
    __syncthreads();
    for (int st = 128; st; st >>= 1) {
        if (threadIdx.x < st) sm[threadIdx.x] += sm[threadIdx.x + st];
        __syncthreads();
    }
    if (threadIdx.x == 0)
        *loss_out = (float)(1.25 * sm[0] / (double)((size_t)B_N * D_N));
}

extern "C" void kernel_launch(void* const* d_in, const int* in_sizes, int n_in,
                              void* d_out, int out_size, void* d_ws, size_t ws_size,
                              hipStream_t stream) {
    const float* X = (const float*)d_in[0];
    const float* E = (const float*)d_in[1];
    float* out = (float*)d_out;
    char* ws = (char*)d_ws;

    u16*    Xsw      = (u16*)d_out;          // 32 MiB scratch in d_out (overwritten by rescore)
    float4* top2     = (float4*)(ws + P_TOP2);
    u16*    Esw      = (u16*)(ws + P_ESW);
    float*  en2f     = (float*)(ws + P_EN2);
    double* partials = (double*)(ws + P_PART);

    xconv_kernel<<<(B_N * 32) / 256, 256, 0, stream>>>(X, Xsw);
    econv_kernel<<<(K_N * 32) / 256, 256, 0, stream>>>(E, Esw);
    en2_kernel<<<K_N / 4, 256, 0, stream>>>(E, en2f);
    dist7_kernel<<<B_N / 64, 256, 0, stream>>>(
        (const char*)Xsw, (const char*)Esw, en2f, top2);
    rescore_kernel<<<512, 256, 0, stream>>>(X, E, top2, out, partials);
    finalize_kernel<<<1, 256, 0, stream>>>(partials, 512, out + (size_t)B_N * D_N);
}

// Round 8
// 170.701 us; speedup vs baseline: 2.0905x; 1.0922x over previous
//
#include <hip/hip_runtime.h>

// VQ-VAE vector quantizer: B=32768, K=4096, D=256 (fp32)
// out = [quantized (B*D floats), vq_loss (1 float)]
//
//  xconv : X -> fp16 hi/lo, swizzled per-64-row-block into d_out (32MB, overwritten later)
//  econv : E -> NEGATED fp16 (hi only), tiled [ct(32)][kb(8)] 8KB frag tiles in ws
//  en2   : en2f[k] = 0.5*||E_k||^2 exact fp32 into ws
//  dist8 : BARRIER-FREE main loop. X (64KB, virtual K=512) resident in LDS
//          (read-only after one prologue barrier). E fragments stream
//          global->register per wave (4x dwordx4/phase, parity-alternating
//          prefetch buffer, compiler-counted vmcnt). 256 phases (32 ct x 8 kb),
//          16 MFMA/wave/phase. v = 0.5||e||^2 - x.e ; single-pass per-row top-2.
//  rescore: fp64 rescore of 2 candidates -> exact winner, gather, loss partials
//  finalize: loss = 1.25 * mean((x-q)^2)

#define B_N 32768
#define K_N 4096
#define D_N 256

typedef _Float16 f16x8 __attribute__((ext_vector_type(8)));
typedef float f32x4 __attribute__((ext_vector_type(4)));
typedef unsigned int uint4v __attribute__((ext_vector_type(4)));
typedef unsigned short u16;

// ws layout (~2.6 MB)
static constexpr size_t P_TOP2 = 0;                               // 32768*16 = 512 KB
static constexpr size_t P_ESW  = (size_t)B_N * 16;                // +2 MB
static constexpr size_t P_EN2  = P_ESW + (size_t)K_N * D_N * 2;   // +16 KB
static constexpr size_t P_PART = P_EN2 + (size_t)K_N * 4;         // +4 KB

__device__ __forceinline__ u16 f2h(float f) {
    _Float16 h = (_Float16)f;
    return __builtin_bit_cast(u16, h);
}
__device__ __forceinline__ float h2f(u16 u) {
    return (float)__builtin_bit_cast(_Float16, u);
}

__device__ __forceinline__ void gload_lds16(const void* g, void* l) {
    __builtin_amdgcn_global_load_lds(
        (const __attribute__((address_space(1))) void*)g,
        (__attribute__((address_space(3))) void*)l, 16, 0, 0);
}

#define WAITVM(N) asm volatile("s_waitcnt vmcnt(" #N ")" ::: "memory")
#define BARRIER() __builtin_amdgcn_s_barrier()

__device__ __forceinline__ void top2_merge(float& v0, int& i0, float& v1, int& i1,
                                           float ov0, int oi0, float ov1, int oi1) {
    bool bf_ = (ov0 < v0) || (ov0 == v0 && oi0 < i0);
    float w0v = bf_ ? ov0 : v0;  int w0i = bf_ ? oi0 : i0;
    float lv  = bf_ ? v0  : ov0; int li  = bf_ ? i0  : oi0;
    float cv  = bf_ ? ov1 : v1;  int ci  = bf_ ? oi1 : i1;
    bool tl = (lv < cv) || (lv == cv && li < ci);
    v0 = w0v; i0 = w0i;
    v1 = tl ? lv : cv; i1 = tl ? li : ci;
}

// ---------- xconv: X -> fp16 hi/lo, 64-row-block tiles ----------
// u16 index = rb*32768 + (term*8 + kb)*2048 + rf*512 + lane*8
// row = rb*64 + rf*16 + llo ; d = kb*32 + lhi*8 + j ; lane = lhi*16+llo
__global__ void xconv_kernel(const float* __restrict__ X, u16* __restrict__ Xsw) {
    const int gid = blockIdx.x * 256 + threadIdx.x;     // B_N*32 threads
    const int row = gid >> 5;
    const int d0  = (gid & 31) << 3;
    const float4 a = *reinterpret_cast<const float4*>(X + (size_t)row * D_N + d0);
    const float4 b = *reinterpret_cast<const float4*>(X + (size_t)row * D_N + d0 + 4);
    float f[8] = {a.x, a.y, a.z, a.w, b.x, b.y, b.z, b.w};
    unsigned hi[8], lo[8];
    #pragma unroll
    for (int j = 0; j < 8; ++j) {
        hi[j] = f2h(f[j]);
        lo[j] = f2h(f[j] - h2f((u16)hi[j]));
    }
    const int rb = row >> 6, rr = row & 63, rf = rr >> 4, llo = rr & 15;
    const int kb = d0 >> 5, lhi = (d0 & 31) >> 3, lane = lhi * 16 + llo;
    size_t base = (size_t)rb * 32768 + (size_t)kb * 2048 + (size_t)rf * 512 + (size_t)lane * 8;
    uint4v hv, lv;
    hv.x = hi[0] | (hi[1] << 16); hv.y = hi[2] | (hi[3] << 16);
    hv.z = hi[4] | (hi[5] << 16); hv.w = hi[6] | (hi[7] << 16);
    lv.x = lo[0] | (lo[1] << 16); lv.y = lo[2] | (lo[3] << 16);
    lv.z = lo[4] | (lo[5] << 16); lv.w = lo[6] | (lo[7] << 16);
    *reinterpret_cast<uint4v*>(Xsw + base) = hv;
    *reinterpret_cast<uint4v*>(Xsw + base + 16384) = lv;   // term stride = 8*2048 u16
}

// ---------- econv: E -> negated fp16 hi, tiled [ct(32)][kb(8)] 8KB tiles ----------
// u16 index = (ct*8+kb)*4096 + cf*512 + lane*8 ; ct = code>>7, cf = (code>>4)&7
__global__ void econv_kernel(const float* __restrict__ E, u16* __restrict__ Esw) {
    const int gid = blockIdx.x * 256 + threadIdx.x;     // K_N*32 threads
    const int code = gid >> 5;
    const int d0  = (gid & 31) << 3;
    const float4 a = *reinterpret_cast<const float4*>(E + (size_t)code * D_N + d0);
    const float4 b = *reinterpret_cast<const float4*>(E + (size_t)code * D_N + d0 + 4);
    float f[8] = {a.x, a.y, a.z, a.w, b.x, b.y, b.z, b.w};
    unsigned hi[8];
    #pragma unroll
    for (int j = 0; j < 8; ++j) hi[j] = f2h(-f[j]);
    const int ct = code >> 7, cf = (code >> 4) & 7, llo = code & 15;
    const int kb = d0 >> 5, lhi = (d0 & 31) >> 3, lane = lhi * 16 + llo;
    size_t base = (size_t)(ct * 8 + kb) * 4096 + (size_t)cf * 512 + (size_t)lane * 8;
    uint4v hv;
    hv.x = hi[0] | (hi[1] << 16); hv.y = hi[2] | (hi[3] << 16);
    hv.z = hi[4] | (hi[5] << 16); hv.w = hi[6] | (hi[7] << 16);
    *reinterpret_cast<uint4v*>(Esw + base) = hv;
}

// ---------- en2: exact fp32 0.5||e||^2 ----------
__global__ void en2_kernel(const float* __restrict__ E, float* __restrict__ en2f) {
    const int gtid = blockIdx.x * blockDim.x + threadIdx.x;
    const int code = gtid >> 6;
    const int lane = threadIdx.x & 63;
    if (code >= K_N) return;
    const float4 v = *reinterpret_cast<const float4*>(E + (size_t)code * D_N + lane * 4);
    double s = (double)v.x * v.x + (double)v.y * v.y + (double)v.z * v.z + (double)v.w * v.w;
    #pragma unroll
    for (int o = 32; o; o >>= 1) s += __shfl_xor(s, o, 64);
    if (lane == 0) en2f[code] = (float)(0.5 * s);
}

// ---------- dist8: barrier-free X-resident GEMM, E global->reg ----------
// 512 blocks, 256 thr = 4 waves (wr=wid>>1, wc=wid&1), wave tile 32 rows x 64 codes.
// LDS 65536 B: X[term2][kb8][rf4][lane64][8]u16 (read-only after prologue).
__launch_bounds__(256, 2)
__global__ void dist8_kernel(const char* __restrict__ Xsw, const char* __restrict__ Esw,
                             const float* __restrict__ en2f, float4* __restrict__ top2) {
    __shared__ __align__(16) char lds[65536];
    const int tid  = threadIdx.x;
    const int lane = tid & 63;
    const int wid  = tid >> 6;          // 0..3
    const int wr   = wid >> 1;          // 0..1 (row half)
    const int wc   = wid & 1;           // 0..1 (code half)
    const int llo  = lane & 15, lhi = lane >> 4;
    const int rb = blockIdx.x;          // 0..511 (64-row group)

    const char* xb = Xsw + (size_t)rb * 65536;
    // per-wave E fragment base: phase p frag j at ep + p*8192 + j*1024
    const char* ep = Esw + (size_t)(wc * 4) * 1024 + (size_t)lane * 16;

    float tv0[8], tv1[8];
    int   tpk[8];
    #pragma unroll
    for (int s = 0; s < 8; ++s) { tv0[s] = 3.4e38f; tv1[s] = 3.4e38f; tpk[s] = -1; }

    f32x4 acc[2][4];
    #pragma unroll
    for (int i = 0; i < 2; ++i)
        #pragma unroll
        for (int j = 0; j < 4; ++j) acc[i][j] = (f32x4){0.f, 0.f, 0.f, 0.f};

    // prologue: X to LDS (64KB), first E phase to regs, en2 for ctile 0
    #pragma unroll
    for (int it = 0; it < 16; ++it)
        gload_lds16(xb + it * 4096 + tid * 16, lds + it * 4096 + wid * 1024);

    f16x8 bv[2][4];
    #pragma unroll
    for (int j = 0; j < 4; ++j)
        bv[0][j] = *reinterpret_cast<const f16x8*>(ep + j * 1024);
    float ena[4], enb[4];
    #pragma unroll
    for (int j = 0; j < 4; ++j) ena[j] = en2f[(wc * 4 + j) * 16 + llo];

    WAITVM(0);      // X resident (also drains bv loads)
    BARRIER();      // the ONLY block-wide barrier before the merge

    const f16x8* LX = reinterpret_cast<const f16x8*>(lds);

    for (int ct = 0; ct < 32; ++ct) {
        #pragma unroll
        for (int kb = 0; kb < 8; ++kb) {
            const int p = ct * 8 + kb;
            // prefetch phase p+1 E frags into the other parity buffer
            if (p < 255) {
                #pragma unroll
                for (int j = 0; j < 4; ++j)
                    bv[(kb + 1) & 1][j] = *reinterpret_cast<const f16x8*>(
                        ep + (size_t)(p + 1) * 8192 + j * 1024);
            }
            if (kb == 6 && ct < 31) {        // prefetch next ctile's en2
                #pragma unroll
                for (int j = 0; j < 4; ++j)
                    enb[j] = en2f[(ct + 1) * 128 + (wc * 4 + j) * 16 + llo];
            }

            __builtin_amdgcn_s_setprio(1);
            #pragma unroll
            for (int term = 0; term < 2; ++term) {
                f16x8 av[2];
                #pragma unroll
                for (int i = 0; i < 2; ++i)
                    av[i] = LX[((term * 8 + kb) * 4 + wr * 2 + i) * 64 + lane];
                #pragma unroll
                for (int i = 0; i < 2; ++i)
                    #pragma unroll
                    for (int j = 0; j < 4; ++j)
                        acc[i][j] = __builtin_amdgcn_mfma_f32_16x16x32_f16(
                            av[i], bv[kb & 1][j], acc[i][j], 0, 0, 0);
            }
            __builtin_amdgcn_s_setprio(0);

            if (kb == 7) {
                // epilogue for ctile ct: v = 0.5||e||^2 - x.e ; per-lane top-2 update
                #pragma unroll
                for (int j = 0; j < 4; ++j) {
                    const int idx = ct * 128 + (wc * 4 + j) * 16 + llo;
                    const float en = ena[j];
                    #pragma unroll
                    for (int i = 0; i < 2; ++i) {
                        #pragma unroll
                        for (int r = 0; r < 4; ++r) {
                            const float v = en + acc[i][j][r];
                            const int s = i * 4 + r;
                            const bool c0 = v < tv0[s];
                            const bool c1 = v < tv1[s];
                            const int pk = tpk[s];
                            const int pkA = (pk << 16) | idx;
                            const int pkB = (idx << 16) | (pk & 0xffff);
                            tv1[s] = c0 ? tv0[s] : (c1 ? v : tv1[s]);
                            tv0[s] = c0 ? v : tv0[s];
                            tpk[s] = c0 ? pkA : (c1 ? pkB : pk);
                        }
                    }
                }
                #pragma unroll
                for (int i = 0; i < 2; ++i)
                    #pragma unroll
                    for (int j = 0; j < 4; ++j) acc[i][j] = (f32x4){0.f, 0.f, 0.f, 0.f};
                #pragma unroll
                for (int j = 0; j < 4; ++j) ena[j] = enb[j];
            }
        }
    }

    // merge the 16 column-lanes (llo) via shfl butterfly
    #pragma unroll
    for (int m = 1; m <= 8; m <<= 1) {
        #pragma unroll
        for (int s = 0; s < 8; ++s) {
            float ov0 = __shfl_xor(tv0[s], m, 64);
            float ov1 = __shfl_xor(tv1[s], m, 64);
            int   opk = __shfl_xor(tpk[s], m, 64);
            float v0 = tv0[s], v1 = tv1[s];
            int i0 = tpk[s] & 0xffff, i1 = (tpk[s] >> 16) & 0xffff;
            top2_merge(v0, i0, v1, i1, ov0, opk & 0xffff, ov1, (opk >> 16) & 0xffff);
            tv0[s] = v0; tv1[s] = v1; tpk[s] = (i1 << 16) | i0;
        }
    }

    __syncthreads();
    float4* M = reinterpret_cast<float4*>(lds);   // [64 rows][2 wc] (reuses X region)
    if (llo == 0) {
        #pragma unroll
        for (int i = 0; i < 2; ++i)
            #pragma unroll
            for (int r = 0; r < 4; ++r) {
                const int rowl = wr * 32 + i * 16 + lhi * 4 + r;
                const int s = i * 4 + r;
                M[rowl * 2 + wc] = make_float4(tv0[s], __int_as_float(tpk[s] & 0xffff),
                                               tv1[s], __int_as_float((tpk[s] >> 16) & 0xffff));
            }
    }
    __syncthreads();
    if (tid < 64) {
        float4 A4 = M[tid * 2 + 0], B4 = M[tid * 2 + 1];
        float v0 = A4.x, v1 = A4.z;
        int i0 = __float_as_int(A4.y), i1 = __float_as_int(A4.w);
        top2_merge(v0, i0, v1, i1, B4.x, __float_as_int(B4.y), B4.z, __float_as_int(B4.w));
        top2[(size_t)(rb * 64 + tid)] =
            make_float4(v0, __int_as_float(i0), v1, __int_as_float(i1));
    }
}

// ---------- rescore: fp64 rescore of 2 candidates ----------
__global__ void rescore_kernel(const float* __restrict__ X, const float* __restrict__ E,
                               const float4* __restrict__ top2, float* __restrict__ out,
                               double* __restrict__ partials) {
    const int lane = threadIdx.x & 63;
    const int wid  = (blockIdx.x * blockDim.x + threadIdx.x) >> 6;
    const int nw   = (gridDim.x * blockDim.x) >> 6;
    double wloc = 0.0;

    for (int row = wid; row < B_N; row += nw) {
        float4 t = top2[row];
        int cand[2] = { __float_as_int(t.y), __float_as_int(t.w) };
        const float4 xv = *reinterpret_cast<const float4*>(X + (size_t)row * D_N + lane * 4);

        double bestd = 1e300; int besti = 0x7fffffff;
        float4 beste = make_float4(0.f, 0.f, 0.f, 0.f);
        #pragma unroll
        for (int c = 0; c < 2; ++c) {
            const int k = cand[c];
            const float4 ev = *reinterpret_cast<const float4*>(E + (size_t)k * D_N + lane * 4);
            double dx = (double)xv.x - (double)ev.x;
            double dy = (double)xv.y - (double)ev.y;
            double dz = (double)xv.z - (double)ev.z;
            double dw = (double)xv.w - (double)ev.w;
            double s = dx * dx + dy * dy + dz * dz + dw * dw;
            #pragma unroll
            for (int o = 32; o; o >>= 1) s += __shfl_xor(s, o, 64);
            if (s < bestd || (s == bestd && k < besti)) { bestd = s; besti = k; beste = ev; }
        }
        *reinterpret_cast<float4*>(out + (size_t)row * D_N + lane * 4) = beste;
        wloc += bestd;
    }

    __shared__ double bsum[8];
    const int widx = threadIdx.x >> 6;
    if (lane == 0) bsum[widx] = wloc;
    __syncthreads();
    if (threadIdx.x == 0) {
        double s = 0.0;
        for (int w = 0; w < (int)(blockDim.x >> 6); ++w) s += bsum[w];
        partials[blockIdx.x] = s;
    }
}

__global__ void finalize_kernel(const double* __restrict__ partials, int n,
                                float* __restrict__ loss_out) {
    __shared__ double sm[256];
    double s = 0.0;
    for (int i = threadIdx.x; i < n; i += 256) s += partials[i];
    sm[threadIdx.x] = s;
    __syncthreads();
    for (int st = 128; st; st >>= 1) {
        if (threadIdx.x < st) sm[threadIdx.x] += sm[threadIdx.x + st];
        __syncthreads();
    }
    if (threadIdx.x == 0)
        *loss_out = (float)(1.25 * sm[0] / (double)((size_t)B_N * D_N));
}

extern "C" void kernel_launch(void* const* d_in, const int* in_sizes, int n_in,
                              void* d_out, int out_size, void* d_ws, size_t ws_size,
                              hipStream_t stream) {
    const float* X = (const float*)d_in[0];
    const float* E = (const float*)d_in[1];
    float* out = (float*)d_out;
    char* ws = (char*)d_ws;

    u16*    Xsw      = (u16*)d_out;          // 32 MiB scratch in d_out (overwritten by rescore)
    float4* top2     = (float4*)(ws + P_TOP2);
    u16*    Esw      = (u16*)(ws + P_ESW);
    float*  en2f     = (float*)(ws + P_EN2);
    double* partials = (double*)(ws + P_PART);

    xconv_kernel<<<(B_N * 32) / 256, 256, 0, stream>>>(X, Xsw);
    econv_kernel<<<(K_N * 32) / 256, 256, 0, stream>>>(E, Esw);
    en2_kernel<<<K_N / 4, 256, 0, stream>>>(E, en2f);
    dist8_kernel<<<B_N / 64, 256, 0, stream>>>(
        (const char*)Xsw, (const char*)Esw, en2f, top2);
    rescore_kernel<<<512, 256, 0, stream>>>(X, E, top2, out, partials);
    finalize_kernel<<<1, 256, 0, stream>>>(partials, 512, out + (size_t)B_N * D_N);
}